// Round 1
// baseline (394.644 us; speedup 1.0000x reference)
//
#include <hip/hip_runtime.h>
#include <math.h>

// ---------------- problem constants ----------------
#define NSEQ  2048
#define DM    512
#define NH    8
#define DK    64
#define MROWS 4096             // B*N = 2*2048
#define BH    16               // B*H
#define BHSTR (NSEQ*DK)        // 131072 elems per (b,h) slab
#define SLAB  (BH*BHSTR)       // 2,097,152
#define EPSF  1e-8f
#define OUT0  (MROWS*DM)       // start of attention region in d_out

typedef __attribute__((ext_vector_type(8))) short short8;
typedef __attribute__((ext_vector_type(4))) float f32x4;
union S8 { short8 v; short s[8]; };
union F4 { f32x4 v; float f[4]; };

// ---------------- static device scratch ----------------
__device__ short g_qh[MROWS*DM], g_ql[MROWS*DM];
__device__ short g_kh[MROWS*DM], g_kl[MROWS*DM];
__device__ short g_vh[MROWS*DM];
__device__ short g_wqh[DM*DM], g_wql[DM*DM];
__device__ short g_wkh[DM*DM], g_wkl[DM*DM];
__device__ short g_wvh[DM*DM], g_woh[DM*DM];
__device__ unsigned short g_Qbf[SLAB];   // bf16( (elu(Q)+1) / (ksum+eps) )  [bh][n][d]
__device__ unsigned short g_Kbf[SLAB];   // bf16( elu(K)+1 )                 [bh][n][d]
__device__ float          g_Vf[SLAB];    // fp32 V heads                     [bh][n][d]
__device__ short          g_OHbf[MROWS*DM]; // bf16 out-heads [b][n][h*64+d]
__device__ float          g_qinv[BH*NSEQ];
__device__ float          g_ksum[BH*DK];
__device__ float          g_KV[BH*DK*DK];

// ---------------- helpers ----------------
__device__ __forceinline__ unsigned short f2bf(float x) {
    union { float f; unsigned u; } v; v.f = x;
    unsigned r = v.u + 0x7fffu + ((v.u >> 16) & 1u);
    return (unsigned short)(r >> 16);
}
__device__ __forceinline__ float bf2f(unsigned short h) {
    union { unsigned u; float f; } v; v.u = ((unsigned)h) << 16; return v.f;
}
__device__ __forceinline__ f32x4 mfma_bf16(short8 a, short8 b, f32x4 c) {
    return __builtin_amdgcn_mfma_f32_16x16x32_bf16(a, b, c, 0, 0, 0);
}
__device__ __forceinline__ float elu1(float x) {
    return (x > 0.f) ? (x + 1.f) : __expf(x);
}
__device__ __forceinline__ void gl_lds16(const void* gsrc, void* ldst) {
    __builtin_amdgcn_global_load_lds(
        (__attribute__((address_space(1))) void*)(unsigned long long)(gsrc),
        (__attribute__((address_space(3))) void*)(unsigned)(unsigned long long)(ldst),
        16, 0, 0);
}

// ---------------- prep: fp32 -> split/plain bf16, zero accumulators ----------------
__global__ __launch_bounds__(256) void prep_kernel(const float* __restrict__ q, const float* __restrict__ k,
                                                   const float* __restrict__ v, const float* __restrict__ wq,
                                                   const float* __restrict__ wk, const float* __restrict__ wv,
                                                   const float* __restrict__ wo) {
    int b = blockIdx.x, t = threadIdx.x;
    if (b < 33) {                       // zero g_KV (65536) + g_ksum (1024)
        int z = b * 2048 + t * 8;
#pragma unroll
        for (int i = 0; i < 8; i++) {
            int zz = z + i;
            if (zz < 65536) g_KV[zz] = 0.f;
            else if (zz < 66560) g_ksum[zz - 65536] = 0.f;
        }
    }
    const float* src; short* hi; short* lo; int off; int split;
    if (b < 1024)      { src = q;  hi = g_qh;  lo = g_ql;  off = b * 2048;          split = 1; }
    else if (b < 2048) { src = k;  hi = g_kh;  lo = g_kl;  off = (b-1024) * 2048;   split = 1; }
    else if (b < 3072) { src = v;  hi = g_vh;  lo = g_vh;  off = (b-2048) * 2048;   split = 0; }
    else if (b < 3200) { src = wq; hi = g_wqh; lo = g_wql; off = (b-3072) * 2048;   split = 1; }
    else if (b < 3328) { src = wk; hi = g_wkh; lo = g_wkl; off = (b-3200) * 2048;   split = 1; }
    else if (b < 3456) { src = wv; hi = g_wvh; lo = g_wvh; off = (b-3328) * 2048;   split = 0; }
    else               { src = wo; hi = g_woh; lo = g_woh; off = (b-3456) * 2048;   split = 0; }
    int idx = off + t * 8;
    F4 a0, a1; a0.v = *(const f32x4*)(src + idx); a1.v = *(const f32x4*)(src + idx + 4);
    S8 h, l;
#pragma unroll
    for (int i = 0; i < 4; i++) {
        unsigned short hb = f2bf(a0.f[i]); h.s[i] = (short)hb;
        l.s[i] = (short)f2bf(a0.f[i] - bf2f(hb));
    }
#pragma unroll
    for (int i = 0; i < 4; i++) {
        unsigned short hb = f2bf(a1.f[i]); h.s[4+i] = (short)hb;
        l.s[4+i] = (short)f2bf(a1.f[i] - bf2f(hb));
    }
    *(short8*)(hi + idx) = h.v;
    if (split) *(short8*)(lo + idx) = l.v;
}

// ---------------- unified MFMA GEMM (unchanged from R2) ----------------
template<int SPLIT>
__global__ __launch_bounds__(256) void gemm_bf16(const float* __restrict__ bias,
                                                 float* __restrict__ dout, int mode) {
    __shared__ short sAh[128*64];
    __shared__ short sBh[64*64];
    __shared__ short sAl[SPLIT ? 128*64 : 8];
    __shared__ short sBl[SPLIT ? 64*64 : 8];

    const short *Ahi, *Alo = nullptr, *Bhi, *Blo = nullptr;
    if (mode == 0)      { Ahi = g_qh;   Alo = g_ql;  Bhi = g_wqh; Blo = g_wql; }
    else if (mode == 1) { Ahi = g_kh;   Alo = g_kl;  Bhi = g_wkh; Blo = g_wkl; }
    else if (mode == 2) { Ahi = g_vh;   Bhi = g_wvh; }
    else                { Ahi = g_OHbf; Bhi = g_woh; }

    int t = threadIdx.x, lane = t & 63, w = t >> 6;
    int l15 = lane & 15, quad = lane >> 4;
    int m0 = blockIdx.x * 128, n0 = blockIdx.y * 64;
    int r_in = lane >> 3, gq = lane & 7;
    int scol = (gq ^ r_in) << 3;

    f32x4 acc[2][4];
    f32x4 z4 = {0.f, 0.f, 0.f, 0.f};
#pragma unroll
    for (int i = 0; i < 2; i++)
#pragma unroll
        for (int j = 0; j < 4; j++) acc[i][j] = z4;

    for (int k0 = 0; k0 < 512; k0 += 64) {
#pragma unroll
        for (int ii = 0; ii < 4; ii++) {
            int i = w * 4 + ii;
            size_t so = (size_t)(m0 + i*8 + r_in) * 512 + k0 + scol;
            gl_lds16(Ahi + so, &sAh[i * 512]);
            if (SPLIT) gl_lds16(Alo + so, &sAl[i * 512]);
        }
#pragma unroll
        for (int ii = 0; ii < 2; ii++) {
            int i = w * 2 + ii;
            size_t so = (size_t)(n0 + i*8 + r_in) * 512 + k0 + scol;
            gl_lds16(Bhi + so, &sBh[i * 512]);
            if (SPLIT) gl_lds16(Blo + so, &sBl[i * 512]);
        }
        __syncthreads();

#pragma unroll
        for (int ks = 0; ks < 2; ks++) {
            int kg = ks * 4 + quad;
            int sw = (kg ^ (l15 & 7)) << 3;
            short8 ah[2], al[2], bh[4], bl[4];
#pragma unroll
            for (int i = 0; i < 2; i++) {
                int ad = (w*32 + i*16 + l15) * 64 + sw;
                ah[i] = *(const short8*)&sAh[ad];
                if (SPLIT) al[i] = *(const short8*)&sAl[ad];
            }
#pragma unroll
            for (int j = 0; j < 4; j++) {
                int ad = (j*16 + l15) * 64 + sw;
                bh[j] = *(const short8*)&sBh[ad];
                if (SPLIT) bl[j] = *(const short8*)&sBl[ad];
            }
#pragma unroll
            for (int i = 0; i < 2; i++)
#pragma unroll
                for (int j = 0; j < 4; j++) {
                    acc[i][j] = mfma_bf16(ah[i], bh[j], acc[i][j]);
                    if (SPLIT) {
                        acc[i][j] = mfma_bf16(ah[i], bl[j], acc[i][j]);
                        acc[i][j] = mfma_bf16(al[i], bh[j], acc[i][j]);
                    }
                }
        }
        __syncthreads();
    }

    int head = blockIdx.y;
    int bh16 = ((m0 >> 11) << 3) + head;
    if (mode == 3) {
#pragma unroll
        for (int j = 0; j < 4; j++) {
            int col = n0 + j*16 + l15;
            float bsv = bias[col];
#pragma unroll
            for (int i = 0; i < 2; i++) {
                F4 v; v.v = acc[i][j];
#pragma unroll
                for (int r = 0; r < 4; r++) {
                    int row = m0 + w*32 + i*16 + quad*4 + r;
                    dout[(size_t)row * 512 + col] = v.f[r] + bsv;
                }
            }
        }
    } else if (mode == 2) {
#pragma unroll
        for (int j = 0; j < 4; j++) {
            int col = n0 + j*16 + l15;
            float bsv = bias[col];
            int dd = col & 63;
#pragma unroll
            for (int i = 0; i < 2; i++) {
                F4 v; v.v = acc[i][j];
#pragma unroll
                for (int r = 0; r < 4; r++) {
                    int nn = (m0 + w*32 + i*16 + quad*4 + r) & 2047;
                    g_Vf[(size_t)bh16 * BHSTR + nn*64 + dd] = v.f[r] + bsv;
                }
            }
        }
    } else {
        float e[2][4][4];
#pragma unroll
        for (int j = 0; j < 4; j++) {
            float bsv = bias[n0 + j*16 + l15];
#pragma unroll
            for (int i = 0; i < 2; i++) {
                F4 v; v.v = acc[i][j];
#pragma unroll
                for (int r = 0; r < 4; r++) e[i][j][r] = elu1(v.f[r] + bsv);
            }
        }
        if (mode == 0) {
            float rks[4];
#pragma unroll
            for (int j = 0; j < 4; j++)
                rks[j] = 1.f / (g_ksum[bh16*64 + j*16 + l15] + EPSF);
#pragma unroll
            for (int i = 0; i < 2; i++) {
#pragma unroll
                for (int r = 0; r < 4; r++) {
                    float s = e[i][0][r] + e[i][1][r] + e[i][2][r] + e[i][3][r];
                    s += __shfl_xor(s, 1); s += __shfl_xor(s, 2);
                    s += __shfl_xor(s, 4); s += __shfl_xor(s, 8);
                    if (l15 == 0) {
                        int nn = (m0 + w*32 + i*16 + quad*4 + r) & 2047;
                        g_qinv[bh16*NSEQ + nn] = 1.f / (s + EPSF);
                    }
                }
#pragma unroll
                for (int j = 0; j < 4; j++) {
                    int dd = j*16 + l15;
#pragma unroll
                    for (int r = 0; r < 4; r++) {
                        int nn = (m0 + w*32 + i*16 + quad*4 + r) & 2047;
                        g_Qbf[(size_t)bh16 * BHSTR + nn*64 + dd] = f2bf(e[i][j][r] * rks[j]);
                    }
                }
            }
        } else { // mode 1
#pragma unroll
            for (int j = 0; j < 4; j++) {
                int dd = j*16 + l15;
                float s = 0.f;
#pragma unroll
                for (int i = 0; i < 2; i++)
#pragma unroll
                    for (int r = 0; r < 4; r++) {
                        int nn = (m0 + w*32 + i*16 + quad*4 + r) & 2047;
                        g_Kbf[(size_t)bh16 * BHSTR + nn*64 + dd] = f2bf(e[i][j][r]);
                        s += e[i][j][r];
                    }
                s += __shfl_xor(s, 16); s += __shfl_xor(s, 32);
                if (lane < 16) atomicAdd(&g_ksum[bh16*64 + dd], s);
            }
        }
    }
}

// ---------------- attention: attn[n,m] = qinv[n]*sum_d Qbf[n,d]*Kbf[m,d] ----------------
// grid (16,16,BH), 128x128 tile, 4 waves of 64x64.
// Epilogue: LDS transpose (64x132 fp32, union'd with staging) -> contiguous
// nontemporal dwordx4 stores (two 512B row segments per inst).
__global__ __launch_bounds__(256) void attn_kernel(float* __restrict__ dout) {
    __shared__ __align__(16) char smem[64*132*4];   // 33792 B >= 32 KB staging
    short* Qs = (short*)smem;                        // 16 KB
    short* Ks = (short*)(smem + 16384);              // 16 KB
    float* Ts = (float*)smem;                        // 64x132 fp32 transpose buffer

    int bh = blockIdx.z;
    int m0 = blockIdx.x * 128, n0 = blockIdx.y * 128;
    int t = threadIdx.x, lane = t & 63, w = t >> 6;
    int l15 = lane & 15, quad = lane >> 4;
    int r_in = lane >> 3, gq = lane & 7;
    int scol = (gq ^ r_in) << 3;

    const short* qb = (const short*)g_Qbf + (size_t)bh * BHSTR;
    const short* kb = (const short*)g_Kbf + (size_t)bh * BHSTR;
#pragma unroll
    for (int ii = 0; ii < 4; ii++) {
        int i = w * 4 + ii;
        gl_lds16(qb + (size_t)(m0 + i*8 + r_in) * 64 + scol, &Qs[i * 512]);
        gl_lds16(kb + (size_t)(n0 + i*8 + r_in) * 64 + scol, &Ks[i * 512]);
    }
    __syncthreads();

    int wm = (w >> 1) * 64, wn = (w & 1) * 64;
    f32x4 acc[4][4];
    f32x4 z4 = {0.f, 0.f, 0.f, 0.f};
#pragma unroll
    for (int i = 0; i < 4; i++)
#pragma unroll
        for (int j = 0; j < 4; j++) acc[i][j] = z4;

#pragma unroll
    for (int ks = 0; ks < 2; ks++) {
        int kg = ks * 4 + quad;
        int sw = (kg ^ (l15 & 7)) << 3;
        short8 qa[4], kbf[4];
#pragma unroll
        for (int i = 0; i < 4; i++) qa[i]  = *(const short8*)&Qs[(wm + i*16 + l15) * 64 + sw];
#pragma unroll
        for (int j = 0; j < 4; j++) kbf[j] = *(const short8*)&Ks[(wn + j*16 + l15) * 64 + sw];
#pragma unroll
        for (int i = 0; i < 4; i++)
#pragma unroll
            for (int j = 0; j < 4; j++) acc[i][j] = mfma_bf16(qa[i], kbf[j], acc[i][j]);
    }

    float* outp = dout + OUT0 + (size_t)bh * NSEQ * NSEQ;
    int halfw = w >> 1;           // which row-half this wave's acc belongs to
    int l31 = lane & 31, lh = lane >> 5;

#pragma unroll
    for (int h = 0; h < 2; h++) {
        __syncthreads();          // staging/prior-pass reads complete before overwrite
        if (halfw == h) {
#pragma unroll
            for (int i = 0; i < 4; i++) {
#pragma unroll
                for (int r2 = 0; r2 < 4; r2++) {
                    int row_l = i*16 + quad*4 + r2;                 // 0..63 in half
                    float qiv = g_qinv[bh*NSEQ + m0 + h*64 + row_l];
#pragma unroll
                    for (int j = 0; j < 4; j++) {
                        F4 v; v.v = acc[i][j];
                        Ts[row_l*132 + wn + j*16 + l15] = v.f[r2] * qiv;
                    }
                }
            }
        }
        __syncthreads();
        // all 4 waves store 16 rows each, 2 rows (2x512B contiguous) per inst
#pragma unroll
        for (int rr = 0; rr < 8; rr++) {
            int row_l = w*16 + rr*2 + lh;
            f32x4 val = *(const f32x4*)&Ts[row_l*132 + l31*4];
            int grow = m0 + h*64 + row_l;
            __builtin_nontemporal_store(val, (f32x4*)(outp + (size_t)grow * NSEQ + n0 + l31*4));
        }
    }
}

// ---------------- KV[e,d] = sum_m Kbf[m,e]*V[m,d], fp32 atomic partials ----------------
__global__ __launch_bounds__(256) void kv_kernel() {
    __shared__ float Ks2[64*64], Vs[64*64];
    int bh = blockIdx.x >> 4, part = blockIdx.x & 15;
    int t = threadIdx.x, d = t & 63, e0 = (t >> 6) * 16;
    float accv[16];
#pragma unroll
    for (int i = 0; i < 16; i++) accv[i] = 0.f;
    int sr = t >> 2, sc = (t & 3) * 16;
    for (int c = 0; c < 2; c++) {
        int nbase = part * 128 + c * 64;
        const unsigned short* kgp = g_Kbf + (size_t)bh * BHSTR + (size_t)(nbase + sr) * 64 + sc;
        const float* vgp = g_Vf + (size_t)bh * BHSTR + (size_t)(nbase + sr) * 64 + sc;
        S8 k0, k1;
        k0.v = *(const short8*)(kgp);
        k1.v = *(const short8*)(kgp + 8);
#pragma unroll
        for (int i = 0; i < 8; i++) Ks2[sr*64 + sc + i]     = bf2f((unsigned short)k0.s[i]);
#pragma unroll
        for (int i = 0; i < 8; i++) Ks2[sr*64 + sc + 8 + i] = bf2f((unsigned short)k1.s[i]);
#pragma unroll
        for (int i = 0; i < 4; i++) *(f32x4*)&Vs[sr*64 + sc + 4*i] = *(const f32x4*)(vgp + 4*i);
        __syncthreads();
#pragma unroll 4
        for (int m = 0; m < 64; m++) {
            float v = Vs[m*64 + d];
            const f32x4* kr = (const f32x4*)&Ks2[m*64 + e0];
            F4 q0, q1, q2, q3;
            q0.v = kr[0]; q1.v = kr[1]; q2.v = kr[2]; q3.v = kr[3];
#pragma unroll
            for (int i = 0; i < 4; i++) accv[i]      += q0.f[i] * v;
#pragma unroll
            for (int i = 0; i < 4; i++) accv[4 + i]  += q1.f[i] * v;
#pragma unroll
            for (int i = 0; i < 4; i++) accv[8 + i]  += q2.f[i] * v;
#pragma unroll
            for (int i = 0; i < 4; i++) accv[12 + i] += q3.f[i] * v;
        }
        __syncthreads();
    }
#pragma unroll
    for (int i = 0; i < 16; i++)
        atomicAdd(&g_KV[bh*4096 + (e0 + i)*64 + d], accv[i]);
}

// ---------------- out-heads: OHbf = bf16( qinv * Qbf @ KV ) ----------------
__global__ __launch_bounds__(256) void oh_kernel() {
    __shared__ float Qs2[128*64];
    __shared__ float KVs[64*64];
    int bh = blockIdx.y, r0 = blockIdx.x * 128;
    int t = threadIdx.x, d = t & 63, w = t >> 6;
    {
        int r = t >> 2, c = (t & 3) * 16;
        const float* s = g_KV + bh*4096 + r*64 + c;
#pragma unroll
        for (int i = 0; i < 4; i++) *(f32x4*)&KVs[r*64 + c + 4*i] = *(const f32x4*)(s + 4*i);
    }
    {
        int r = t >> 1, c = (t & 1) * 32;
        const unsigned short* s = g_Qbf + (size_t)bh * BHSTR + (size_t)(r0 + r) * 64 + c;
#pragma unroll
        for (int i = 0; i < 4; i++) {
            S8 x; x.v = *(const short8*)(s + 8*i);
#pragma unroll
            for (int j = 0; j < 8; j++) Qs2[r*64 + c + 8*i + j] = bf2f((unsigned short)x.s[j]);
        }
    }
    __syncthreads();
    float kvc[64];
#pragma unroll
    for (int e = 0; e < 64; e++) kvc[e] = KVs[e*64 + d];
    int b = bh >> 3, h = bh & 7;
    for (int rr = 0; rr < 32; rr++) {
        int row = w * 32 + rr;
        const f32x4* qr = (const f32x4*)&Qs2[row*64];
        float a = 0.f;
#pragma unroll
        for (int e4 = 0; e4 < 16; e4++) {
            F4 q; q.v = qr[e4];
            a += q.f[0]*kvc[4*e4] + q.f[1]*kvc[4*e4+1] + q.f[2]*kvc[4*e4+2] + q.f[3]*kvc[4*e4+3];
        }
        int grow = r0 + row;
        float val = a * g_qinv[bh*NSEQ + grow];
        g_OHbf[((size_t)b*NSEQ + grow)*512 + h*64 + d] = (short)f2bf(val);
    }
}

// ---------------- launch ----------------
extern "C" void kernel_launch(void* const* d_in, const int* in_sizes, int n_in,
                              void* d_out, int out_size, void* d_ws, size_t ws_size,
                              hipStream_t stream) {
    const float* q  = (const float*)d_in[0];
    const float* k  = (const float*)d_in[1];
    const float* v  = (const float*)d_in[2];
    const float* Wq = (const float*)d_in[3];
    const float* bq = (const float*)d_in[4];
    const float* Wk = (const float*)d_in[5];
    const float* bk = (const float*)d_in[6];
    const float* Wv = (const float*)d_in[7];
    const float* bv = (const float*)d_in[8];
    const float* Wo = (const float*)d_in[9];
    const float* bo = (const float*)d_in[10];
    float* out = (float*)d_out;

    prep_kernel<<<3584, 256, 0, stream>>>(q, k, v, Wq, Wk, Wv, Wo);

    dim3 gproj(32, 8);
    gemm_bf16<1><<<gproj, 256, 0, stream>>>(bk, nullptr, 1);   // K (produces ksum)
    gemm_bf16<1><<<gproj, 256, 0, stream>>>(bq, nullptr, 0);   // Q (consumes ksum)
    gemm_bf16<0><<<gproj, 256, 0, stream>>>(bv, nullptr, 2);   // V

    attn_kernel<<<dim3(16, 16, BH), 256, 0, stream>>>(out);

    kv_kernel<<<256, 256, 0, stream>>>();
    oh_kernel<<<dim3(16, BH), 256, 0, stream>>>();

    gemm_bf16<0><<<gproj, 256, 0, stream>>>(bo, out, 3);       // final projection
}

// Round 2
// 392.377 us; speedup vs baseline: 1.0058x; 1.0058x over previous
//
#include <hip/hip_runtime.h>
#include <math.h>

// ---------------- problem constants ----------------
#define NSEQ  2048
#define DM    512
#define NH    8
#define DK    64
#define MROWS 4096             // B*N = 2*2048
#define BH    16               // B*H
#define BHSTR (NSEQ*DK)        // 131072 elems per (b,h) slab
#define SLAB  (BH*BHSTR)       // 2,097,152
#define EPSF  1e-8f
#define OUT0  (MROWS*DM)       // start of attention region in d_out

typedef __attribute__((ext_vector_type(8))) short short8;
typedef __attribute__((ext_vector_type(4))) float f32x4;
union S8 { short8 v; short s[8]; };
union F4 { f32x4 v; float f[4]; };

// ---------------- static device scratch ----------------
__device__ short g_qh[MROWS*DM], g_ql[MROWS*DM];
__device__ short g_kh[MROWS*DM], g_kl[MROWS*DM];
__device__ short g_vh[MROWS*DM];
__device__ short g_wqh[DM*DM], g_wql[DM*DM];
__device__ short g_wkh[DM*DM], g_wkl[DM*DM];
__device__ short g_wvh[DM*DM], g_woh[DM*DM];
__device__ unsigned short g_Qbf[SLAB];   // bf16( (elu(Q)+1) / (ksum+eps) )  [bh][n][d]
__device__ unsigned short g_Kbf[SLAB];   // bf16( elu(K)+1 )                 [bh][n][d]
__device__ float          g_Vf[SLAB];    // fp32 V heads                     [bh][n][d]
__device__ short          g_OHbf[MROWS*DM]; // bf16 out-heads [b][n][h*64+d]
__device__ float          g_qinv[BH*NSEQ];
__device__ float          g_ksum[BH*DK];
__device__ float          g_KV[BH*DK*DK];

// ---------------- helpers ----------------
__device__ __forceinline__ unsigned short f2bf(float x) {
    union { float f; unsigned u; } v; v.f = x;
    unsigned r = v.u + 0x7fffu + ((v.u >> 16) & 1u);
    return (unsigned short)(r >> 16);
}
__device__ __forceinline__ float bf2f(unsigned short h) {
    union { unsigned u; float f; } v; v.u = ((unsigned)h) << 16; return v.f;
}
__device__ __forceinline__ f32x4 mfma_bf16(short8 a, short8 b, f32x4 c) {
    return __builtin_amdgcn_mfma_f32_16x16x32_bf16(a, b, c, 0, 0, 0);
}
__device__ __forceinline__ float elu1(float x) {
    return (x > 0.f) ? (x + 1.f) : __expf(x);
}
__device__ __forceinline__ void gl_lds16(const void* gsrc, void* ldst) {
    __builtin_amdgcn_global_load_lds(
        (__attribute__((address_space(1))) void*)(unsigned long long)(gsrc),
        (__attribute__((address_space(3))) void*)(unsigned)(unsigned long long)(ldst),
        16, 0, 0);
}

// ---------------- prep: fp32 -> split/plain bf16, zero accumulators ----------------
__global__ __launch_bounds__(256) void prep_kernel(const float* __restrict__ q, const float* __restrict__ k,
                                                   const float* __restrict__ v, const float* __restrict__ wq,
                                                   const float* __restrict__ wk, const float* __restrict__ wv,
                                                   const float* __restrict__ wo) {
    int b = blockIdx.x, t = threadIdx.x;
    if (b < 33) {                       // zero g_KV (65536) + g_ksum (1024)
        int z = b * 2048 + t * 8;
#pragma unroll
        for (int i = 0; i < 8; i++) {
            int zz = z + i;
            if (zz < 65536) g_KV[zz] = 0.f;
            else if (zz < 66560) g_ksum[zz - 65536] = 0.f;
        }
    }
    const float* src; short* hi; short* lo; int off; int split;
    if (b < 1024)      { src = q;  hi = g_qh;  lo = g_ql;  off = b * 2048;          split = 1; }
    else if (b < 2048) { src = k;  hi = g_kh;  lo = g_kl;  off = (b-1024) * 2048;   split = 1; }
    else if (b < 3072) { src = v;  hi = g_vh;  lo = g_vh;  off = (b-2048) * 2048;   split = 0; }
    else if (b < 3200) { src = wq; hi = g_wqh; lo = g_wql; off = (b-3072) * 2048;   split = 1; }
    else if (b < 3328) { src = wk; hi = g_wkh; lo = g_wkl; off = (b-3200) * 2048;   split = 1; }
    else if (b < 3456) { src = wv; hi = g_wvh; lo = g_wvh; off = (b-3328) * 2048;   split = 0; }
    else               { src = wo; hi = g_woh; lo = g_woh; off = (b-3456) * 2048;   split = 0; }
    int idx = off + t * 8;
    F4 a0, a1; a0.v = *(const f32x4*)(src + idx); a1.v = *(const f32x4*)(src + idx + 4);
    S8 h, l;
#pragma unroll
    for (int i = 0; i < 4; i++) {
        unsigned short hb = f2bf(a0.f[i]); h.s[i] = (short)hb;
        l.s[i] = (short)f2bf(a0.f[i] - bf2f(hb));
    }
#pragma unroll
    for (int i = 0; i < 4; i++) {
        unsigned short hb = f2bf(a1.f[i]); h.s[4+i] = (short)hb;
        l.s[4+i] = (short)f2bf(a1.f[i] - bf2f(hb));
    }
    *(short8*)(hi + idx) = h.v;
    if (split) *(short8*)(lo + idx) = l.v;
}

// ---------------- unified MFMA GEMM ----------------
// Runtime mode select via blockIdx.z so independent GEMMs (K and V projections)
// fuse into ONE launch: 512 blocks = 2 blocks/CU, barrier drains of one block
// hide under the other's MFMA/loads. split is a runtime uniform branch.
__global__ __launch_bounds__(256) void gemm_bf16(const float* __restrict__ biasA,
                                                 const float* __restrict__ biasB,
                                                 float* __restrict__ dout,
                                                 int modeA, int modeB) {
    __shared__ short sAh[128*64];
    __shared__ short sBh[64*64];
    __shared__ short sAl[128*64];
    __shared__ short sBl[64*64];

    int mode = (blockIdx.z == 0) ? modeA : modeB;
    const float* bias = (blockIdx.z == 0) ? biasA : biasB;
    const int split = (mode == 0 || mode == 1);

    const short *Ahi, *Alo = nullptr, *Bhi, *Blo = nullptr;
    if (mode == 0)      { Ahi = g_qh;   Alo = g_ql;  Bhi = g_wqh; Blo = g_wql; }
    else if (mode == 1) { Ahi = g_kh;   Alo = g_kl;  Bhi = g_wkh; Blo = g_wkl; }
    else if (mode == 2) { Ahi = g_vh;   Bhi = g_wvh; }
    else                { Ahi = g_OHbf; Bhi = g_woh; }

    int t = threadIdx.x, lane = t & 63, w = t >> 6;
    int l15 = lane & 15, quad = lane >> 4;
    int m0 = blockIdx.x * 128, n0 = blockIdx.y * 64;
    int r_in = lane >> 3, gq = lane & 7;
    int scol = (gq ^ r_in) << 3;

    f32x4 acc[2][4];
    f32x4 z4 = {0.f, 0.f, 0.f, 0.f};
#pragma unroll
    for (int i = 0; i < 2; i++)
#pragma unroll
        for (int j = 0; j < 4; j++) acc[i][j] = z4;

    for (int k0 = 0; k0 < 512; k0 += 64) {
#pragma unroll
        for (int ii = 0; ii < 4; ii++) {
            int i = w * 4 + ii;
            size_t so = (size_t)(m0 + i*8 + r_in) * 512 + k0 + scol;
            gl_lds16(Ahi + so, &sAh[i * 512]);
            if (split) gl_lds16(Alo + so, &sAl[i * 512]);
        }
#pragma unroll
        for (int ii = 0; ii < 2; ii++) {
            int i = w * 2 + ii;
            size_t so = (size_t)(n0 + i*8 + r_in) * 512 + k0 + scol;
            gl_lds16(Bhi + so, &sBh[i * 512]);
            if (split) gl_lds16(Blo + so, &sBl[i * 512]);
        }
        __syncthreads();

#pragma unroll
        for (int ks = 0; ks < 2; ks++) {
            int kg = ks * 4 + quad;
            int sw = (kg ^ (l15 & 7)) << 3;
            short8 ah[2], al[2], bh[4], bl[4];
#pragma unroll
            for (int i = 0; i < 2; i++) {
                int ad = (w*32 + i*16 + l15) * 64 + sw;
                ah[i] = *(const short8*)&sAh[ad];
                if (split) al[i] = *(const short8*)&sAl[ad];
            }
#pragma unroll
            for (int j = 0; j < 4; j++) {
                int ad = (j*16 + l15) * 64 + sw;
                bh[j] = *(const short8*)&sBh[ad];
                if (split) bl[j] = *(const short8*)&sBl[ad];
            }
#pragma unroll
            for (int i = 0; i < 2; i++)
#pragma unroll
                for (int j = 0; j < 4; j++) {
                    acc[i][j] = mfma_bf16(ah[i], bh[j], acc[i][j]);
                    if (split) {
                        acc[i][j] = mfma_bf16(ah[i], bl[j], acc[i][j]);
                        acc[i][j] = mfma_bf16(al[i], bh[j], acc[i][j]);
                    }
                }
        }
        __syncthreads();
    }

    int head = blockIdx.y;
    int bh16 = ((m0 >> 11) << 3) + head;
    if (mode == 3) {
#pragma unroll
        for (int j = 0; j < 4; j++) {
            int col = n0 + j*16 + l15;
            float bsv = bias[col];
#pragma unroll
            for (int i = 0; i < 2; i++) {
                F4 v; v.v = acc[i][j];
#pragma unroll
                for (int r = 0; r < 4; r++) {
                    int row = m0 + w*32 + i*16 + quad*4 + r;
                    dout[(size_t)row * 512 + col] = v.f[r] + bsv;
                }
            }
        }
    } else if (mode == 2) {
#pragma unroll
        for (int j = 0; j < 4; j++) {
            int col = n0 + j*16 + l15;
            float bsv = bias[col];
            int dd = col & 63;
#pragma unroll
            for (int i = 0; i < 2; i++) {
                F4 v; v.v = acc[i][j];
#pragma unroll
                for (int r = 0; r < 4; r++) {
                    int nn = (m0 + w*32 + i*16 + quad*4 + r) & 2047;
                    g_Vf[(size_t)bh16 * BHSTR + nn*64 + dd] = v.f[r] + bsv;
                }
            }
        }
    } else {
        float e[2][4][4];
#pragma unroll
        for (int j = 0; j < 4; j++) {
            float bsv = bias[n0 + j*16 + l15];
#pragma unroll
            for (int i = 0; i < 2; i++) {
                F4 v; v.v = acc[i][j];
#pragma unroll
                for (int r = 0; r < 4; r++) e[i][j][r] = elu1(v.f[r] + bsv);
            }
        }
        if (mode == 0) {
            float rks[4];
#pragma unroll
            for (int j = 0; j < 4; j++)
                rks[j] = 1.f / (g_ksum[bh16*64 + j*16 + l15] + EPSF);
#pragma unroll
            for (int i = 0; i < 2; i++) {
#pragma unroll
                for (int r = 0; r < 4; r++) {
                    float s = e[i][0][r] + e[i][1][r] + e[i][2][r] + e[i][3][r];
                    s += __shfl_xor(s, 1); s += __shfl_xor(s, 2);
                    s += __shfl_xor(s, 4); s += __shfl_xor(s, 8);
                    if (l15 == 0) {
                        int nn = (m0 + w*32 + i*16 + quad*4 + r) & 2047;
                        g_qinv[bh16*NSEQ + nn] = 1.f / (s + EPSF);
                    }
                }
#pragma unroll
                for (int j = 0; j < 4; j++) {
                    int dd = j*16 + l15;
#pragma unroll
                    for (int r = 0; r < 4; r++) {
                        int nn = (m0 + w*32 + i*16 + quad*4 + r) & 2047;
                        g_Qbf[(size_t)bh16 * BHSTR + nn*64 + dd] = f2bf(e[i][j][r] * rks[j]);
                    }
                }
            }
        } else { // mode 1
#pragma unroll
            for (int j = 0; j < 4; j++) {
                int dd = j*16 + l15;
                float s = 0.f;
#pragma unroll
                for (int i = 0; i < 2; i++)
#pragma unroll
                    for (int r = 0; r < 4; r++) {
                        int nn = (m0 + w*32 + i*16 + quad*4 + r) & 2047;
                        g_Kbf[(size_t)bh16 * BHSTR + nn*64 + dd] = f2bf(e[i][j][r]);
                        s += e[i][j][r];
                    }
                s += __shfl_xor(s, 16); s += __shfl_xor(s, 32);
                if (lane < 16) atomicAdd(&g_ksum[bh16*64 + dd], s);
            }
        }
    }
}

// ---------------- attention: attn[n,m] = qinv[n]*sum_d Qbf[n,d]*Kbf[m,d] ----------------
// grid (16,16,BH), 128x128 tile, 4 waves of 64x64.
// XCD-aware bijective swizzle (4096 blocks % 8 XCDs == 0): each XCD gets a
// contiguous 512-block chunk = 2 complete (b,h) slabs (~1 MB Q+K) -> L2-resident,
// K-tile re-reads across m-blocks become same-XCD L2 hits.
// Epilogue: LDS transpose (64x132 fp32, union'd with staging) -> contiguous
// nontemporal dwordx4 stores (two 512B row segments per inst).
__global__ __launch_bounds__(256) void attn_kernel(float* __restrict__ dout) {
    __shared__ __align__(16) char smem[64*132*4];   // 33792 B >= 32 KB staging
    short* Qs = (short*)smem;                        // 16 KB
    short* Ks = (short*)(smem + 16384);              // 16 KB
    float* Ts = (float*)smem;                        // 64x132 fp32 transpose buffer

    int fid = blockIdx.x + (blockIdx.y << 4) + (blockIdx.z << 8);
    int sid = (fid & 7) * 512 + (fid >> 3);          // bijective: 4096 % 8 == 0
    int bh = sid >> 8;
    int m0 = (sid & 15) << 7;                        // m fastest within XCD chunk
    int n0 = ((sid >> 4) & 15) << 7;

    int t = threadIdx.x, lane = t & 63, w = t >> 6;
    int l15 = lane & 15, quad = lane >> 4;
    int r_in = lane >> 3, gq = lane & 7;
    int scol = (gq ^ r_in) << 3;

    const short* qb = (const short*)g_Qbf + (size_t)bh * BHSTR;
    const short* kb = (const short*)g_Kbf + (size_t)bh * BHSTR;
#pragma unroll
    for (int ii = 0; ii < 4; ii++) {
        int i = w * 4 + ii;
        gl_lds16(qb + (size_t)(m0 + i*8 + r_in) * 64 + scol, &Qs[i * 512]);
        gl_lds16(kb + (size_t)(n0 + i*8 + r_in) * 64 + scol, &Ks[i * 512]);
    }
    __syncthreads();

    int wm = (w >> 1) * 64, wn = (w & 1) * 64;
    f32x4 acc[4][4];
    f32x4 z4 = {0.f, 0.f, 0.f, 0.f};
#pragma unroll
    for (int i = 0; i < 4; i++)
#pragma unroll
        for (int j = 0; j < 4; j++) acc[i][j] = z4;

#pragma unroll
    for (int ks = 0; ks < 2; ks++) {
        int kg = ks * 4 + quad;
        int sw = (kg ^ (l15 & 7)) << 3;
        short8 qa[4], kbf[4];
#pragma unroll
        for (int i = 0; i < 4; i++) qa[i]  = *(const short8*)&Qs[(wm + i*16 + l15) * 64 + sw];
#pragma unroll
        for (int j = 0; j < 4; j++) kbf[j] = *(const short8*)&Ks[(wn + j*16 + l15) * 64 + sw];
#pragma unroll
        for (int i = 0; i < 4; i++)
#pragma unroll
            for (int j = 0; j < 4; j++) acc[i][j] = mfma_bf16(qa[i], kbf[j], acc[i][j]);
    }

    float* outp = dout + OUT0 + (size_t)bh * NSEQ * NSEQ;
    int halfw = w >> 1;           // which row-half this wave's acc belongs to
    int l31 = lane & 31, lh = lane >> 5;

#pragma unroll
    for (int h = 0; h < 2; h++) {
        __syncthreads();          // staging/prior-pass reads complete before overwrite
        if (halfw == h) {
#pragma unroll
            for (int i = 0; i < 4; i++) {
#pragma unroll
                for (int r2 = 0; r2 < 4; r2++) {
                    int row_l = i*16 + quad*4 + r2;                 // 0..63 in half
                    float qiv = g_qinv[bh*NSEQ + m0 + h*64 + row_l];
#pragma unroll
                    for (int j = 0; j < 4; j++) {
                        F4 v; v.v = acc[i][j];
                        Ts[row_l*132 + wn + j*16 + l15] = v.f[r2] * qiv;
                    }
                }
            }
        }
        __syncthreads();
        // all 4 waves store 16 rows each, 2 rows (2x512B contiguous) per inst
#pragma unroll
        for (int rr = 0; rr < 8; rr++) {
            int row_l = w*16 + rr*2 + lh;
            f32x4 val = *(const f32x4*)&Ts[row_l*132 + l31*4];
            int grow = m0 + h*64 + row_l;
            __builtin_nontemporal_store(val, (f32x4*)(outp + (size_t)grow * NSEQ + n0 + l31*4));
        }
    }
}

// ---------------- KV[e,d] = sum_m Kbf[m,e]*V[m,d], fp32 atomic partials ----------------
__global__ __launch_bounds__(256) void kv_kernel() {
    __shared__ float Ks2[64*64], Vs[64*64];
    int bh = blockIdx.x >> 4, part = blockIdx.x & 15;
    int t = threadIdx.x, d = t & 63, e0 = (t >> 6) * 16;
    float accv[16];
#pragma unroll
    for (int i = 0; i < 16; i++) accv[i] = 0.f;
    int sr = t >> 2, sc = (t & 3) * 16;
    for (int c = 0; c < 2; c++) {
        int nbase = part * 128 + c * 64;
        const unsigned short* kgp = g_Kbf + (size_t)bh * BHSTR + (size_t)(nbase + sr) * 64 + sc;
        const float* vgp = g_Vf + (size_t)bh * BHSTR + (size_t)(nbase + sr) * 64 + sc;
        S8 k0, k1;
        k0.v = *(const short8*)(kgp);
        k1.v = *(const short8*)(kgp + 8);
#pragma unroll
        for (int i = 0; i < 8; i++) Ks2[sr*64 + sc + i]     = bf2f((unsigned short)k0.s[i]);
#pragma unroll
        for (int i = 0; i < 8; i++) Ks2[sr*64 + sc + 8 + i] = bf2f((unsigned short)k1.s[i]);
#pragma unroll
        for (int i = 0; i < 4; i++) *(f32x4*)&Vs[sr*64 + sc + 4*i] = *(const f32x4*)(vgp + 4*i);
        __syncthreads();
#pragma unroll 4
        for (int m = 0; m < 64; m++) {
            float v = Vs[m*64 + d];
            const f32x4* kr = (const f32x4*)&Ks2[m*64 + e0];
            F4 q0, q1, q2, q3;
            q0.v = kr[0]; q1.v = kr[1]; q2.v = kr[2]; q3.v = kr[3];
#pragma unroll
            for (int i = 0; i < 4; i++) accv[i]      += q0.f[i] * v;
#pragma unroll
            for (int i = 0; i < 4; i++) accv[4 + i]  += q1.f[i] * v;
#pragma unroll
            for (int i = 0; i < 4; i++) accv[8 + i]  += q2.f[i] * v;
#pragma unroll
            for (int i = 0; i < 4; i++) accv[12 + i] += q3.f[i] * v;
        }
        __syncthreads();
    }
#pragma unroll
    for (int i = 0; i < 16; i++)
        atomicAdd(&g_KV[bh*4096 + (e0 + i)*64 + d], accv[i]);
}

// ---------------- out-heads: OHbf = bf16( qinv * Qbf @ KV ) ----------------
__global__ __launch_bounds__(256) void oh_kernel() {
    __shared__ float Qs2[128*64];
    __shared__ float KVs[64*64];
    int bh = blockIdx.y, r0 = blockIdx.x * 128;
    int t = threadIdx.x, d = t & 63, w = t >> 6;
    {
        int r = t >> 2, c = (t & 3) * 16;
        const float* s = g_KV + bh*4096 + r*64 + c;
#pragma unroll
        for (int i = 0; i < 4; i++) *(f32x4*)&KVs[r*64 + c + 4*i] = *(const f32x4*)(s + 4*i);
    }
    {
        int r = t >> 1, c = (t & 1) * 32;
        const unsigned short* s = g_Qbf + (size_t)bh * BHSTR + (size_t)(r0 + r) * 64 + c;
#pragma unroll
        for (int i = 0; i < 4; i++) {
            S8 x; x.v = *(const short8*)(s + 8*i);
#pragma unroll
            for (int j = 0; j < 8; j++) Qs2[r*64 + c + 8*i + j] = bf2f((unsigned short)x.s[j]);
        }
    }
    __syncthreads();
    float kvc[64];
#pragma unroll
    for (int e = 0; e < 64; e++) kvc[e] = KVs[e*64 + d];
    int b = bh >> 3, h = bh & 7;
    for (int rr = 0; rr < 32; rr++) {
        int row = w * 32 + rr;
        const f32x4* qr = (const f32x4*)&Qs2[row*64];
        float a = 0.f;
#pragma unroll
        for (int e4 = 0; e4 < 16; e4++) {
            F4 q; q.v = qr[e4];
            a += q.f[0]*kvc[4*e4] + q.f[1]*kvc[4*e4+1] + q.f[2]*kvc[4*e4+2] + q.f[3]*kvc[4*e4+3];
        }
        int grow = r0 + row;
        float val = a * g_qinv[bh*NSEQ + grow];
        g_OHbf[((size_t)b*NSEQ + grow)*512 + h*64 + d] = (short)f2bf(val);
    }
}

// ---------------- launch ----------------
extern "C" void kernel_launch(void* const* d_in, const int* in_sizes, int n_in,
                              void* d_out, int out_size, void* d_ws, size_t ws_size,
                              hipStream_t stream) {
    const float* q  = (const float*)d_in[0];
    const float* k  = (const float*)d_in[1];
    const float* v  = (const float*)d_in[2];
    const float* Wq = (const float*)d_in[3];
    const float* bq = (const float*)d_in[4];
    const float* Wk = (const float*)d_in[5];
    const float* bk = (const float*)d_in[6];
    const float* Wv = (const float*)d_in[7];
    const float* bv = (const float*)d_in[8];
    const float* Wo = (const float*)d_in[9];
    const float* bo = (const float*)d_in[10];
    float* out = (float*)d_out;

    prep_kernel<<<3584, 256, 0, stream>>>(q, k, v, Wq, Wk, Wv, Wo);

    // K + V projections fused: 512 blocks = 2 blocks/CU (was 2 launches @ 1/CU)
    gemm_bf16<<<dim3(32, 8, 2), 256, 0, stream>>>(bk, bv, nullptr, 1, 2);
    // Q projection (consumes ksum from K)
    gemm_bf16<<<dim3(32, 8, 1), 256, 0, stream>>>(bq, bq, nullptr, 0, 0);

    attn_kernel<<<dim3(16, 16, BH), 256, 0, stream>>>(out);

    kv_kernel<<<256, 256, 0, stream>>>();
    oh_kernel<<<dim3(16, BH), 256, 0, stream>>>();

    // final projection
    gemm_bf16<<<dim3(32, 8, 1), 256, 0, stream>>>(bo, bo, out, 3, 3);
}